// Round 12
// baseline (3418.000 us; speedup 1.0000x reference)
//
#include <hip/hip_runtime.h>
#include <hip/hip_bf16.h>

typedef __attribute__((ext_vector_type(4))) float f32x4;
typedef __attribute__((ext_vector_type(8))) short short8;
typedef __attribute__((ext_vector_type(8))) unsigned short ushort8;

#define T_STEPS 512
#define BATCH   128
#define IDIM    512
#define HDIM    1024
#define KTOT    1536           // IDIM + HDIM (fused [x_t | h] @ [Wx; Wh])
#define NGROUP  8              // batch groups (16 rows each)
#define GROWS   16             // batch rows per group
#define NCB     8              // column-blocks per group (128 cols each)
#define CBW     128            // output columns per block (8 waves x 16)
#define NBLK    (NGROUP * NCB) // 64 blocks
#define HBUF_ELEMS (BATCH * HDIM)
#define XBUFB   (GROWS * IDIM * 2)   // bytes per xs half
#define NFLAG   (NGROUP * 64)        // per-WAVE flags (8 blocks x 8 waves per group)
// handshake scratch appended after flags: xcdmap[NBLK], hsflag[NBLK]

// f32 -> bf16 round-to-nearest-even
__device__ __forceinline__ unsigned short f2bf(float f) {
    unsigned int u = __builtin_bit_cast(unsigned int, f);
    u = (u + 0x7FFFu + ((u >> 16) & 1u)) >> 16;
    return (unsigned short)u;
}

// fast tanh: clamp +-9, e2x = exp2(2*log2e*x), (e2x-1)*rcp(e2x+1).
__device__ __forceinline__ float fast_tanh(float x) {
    x = fminf(9.0f, fmaxf(-9.0f, x));
    float t = __builtin_exp2f(x * 2.8853900817779268f);
    return (t - 1.0f) * __builtin_amdgcn_rcpf(t + 1.0f);
}

// XOR swizzles (row strides 0 mod 128B; XOR row low-bits into the 16B-slot index)
__device__ __forceinline__ int swzX(int row, int c) { return row * 1024 + (c ^ ((row & 7) << 4)); }
__device__ __forceinline__ int swzH(int row, int c) { return row * 2048 + (c ^ ((row & 7) << 4)); }

// ---- coherence primitives ---------------------------------------------------
// Session model (validated R8+R9): sc0 sc1 STORES write through to HBM and
// their vmcnt ack costs ~1100cy; PLAIN stores ack at the shared same-XCD L2
// (~250cy) and sc0 sc1 (L1-bypassing) consumer loads dirty-hit that line.
// R8: h-data plain (WRITE 139.5->9.2MB, -182us). R9: flag publish plain
// (WRITE ->1MB, -387us). R10: NEVER put work between drain and publish.
// R11 LESSON: VGPR_Count must be >= ~160 for the pinned Bf[48] (192 VGPRs);
// 512-thread blocks need __launch_bounds__(512,2) or the compiler caps at
// 128 and spills Bf to scratch (8.4MB WRITE spill-out signature, 2.1x time).
__device__ __forceinline__ void st_u32_if(unsigned int* p, unsigned int v) {
    asm volatile("global_store_dword %0, %1, off sc0 sc1" :: "v"(p), "v"(v) : "memory");
}
template<bool FAST>
__device__ __forceinline__ void st_u32_c(unsigned int* p, unsigned int v) {
    if (FAST) asm volatile("global_store_dword %0, %1, off" :: "v"(p), "v"(v) : "memory");
    else      asm volatile("global_store_dword %0, %1, off sc0 sc1" :: "v"(p), "v"(v) : "memory");
}
template<bool FAST>
__device__ __forceinline__ void st_h16_c(unsigned short* p, unsigned short v) {
    if (FAST) asm volatile("global_store_short %0, %1, off" :: "v"(p), "v"(v) : "memory");
    else      asm volatile("global_store_short %0, %1, off sc0 sc1" :: "v"(p), "v"(v) : "memory");
}
__device__ __forceinline__ unsigned int ld_u32_if(const unsigned int* p) {
    unsigned int v;
    asm volatile("global_load_dword %0, %1, off sc0 sc1\n\ts_waitcnt vmcnt(0)"
                 : "=v"(v) : "v"(p) : "memory");
    return v;
}
// issue 4 pipelined dwordx4 h-slice loads (64 B), NO wait (counted vmcnt)
__device__ __forceinline__ void ldh_issue_if(const unsigned short* p, ushort8 v[4]) {
    asm volatile(
        "global_load_dwordx4 %0, %4, off sc0 sc1\n\t"
        "global_load_dwordx4 %1, %4, off offset:16 sc0 sc1\n\t"
        "global_load_dwordx4 %2, %4, off offset:32 sc0 sc1\n\t"
        "global_load_dwordx4 %3, %4, off offset:48 sc0 sc1"
        : "=&v"(v[0]), "=&v"(v[1]), "=&v"(v[2]), "=&v"(v[3])
        : "v"(p) : "memory");
}
// issue 4 pipelined dwordx4 x-slice loads (64 B of f32), normal caching, NO wait
__device__ __forceinline__ void ldx_issue(const float* p, float4 v[4]) {
    asm volatile(
        "global_load_dwordx4 %0, %4, off\n\t"
        "global_load_dwordx4 %1, %4, off offset:16\n\t"
        "global_load_dwordx4 %2, %4, off offset:32\n\t"
        "global_load_dwordx4 %3, %4, off offset:48"
        : "=&v"(v[0]), "=&v"(v[1]), "=&v"(v[2]), "=&v"(v[3])
        : "v"(p) : "memory");
}

// ---------------------------------------------------------------------------
// Prep: WT[n][k] = bf16(W[k][n]) for W in {Wx (koff=0), Wh (koff=IDIM)}.
__global__ void prep_transpose(const float* __restrict__ src,
                               unsigned short* __restrict__ dst, int koff) {
    __shared__ float tl[32][33];
    const int tx = threadIdx.x, ty = threadIdx.y;
    const int k0 = blockIdx.x * 32, n0 = blockIdx.y * 32;
#pragma unroll
    for (int q = 0; q < 4; ++q) {
        int kk = ty * 4 + q;
        tl[kk][tx] = src[(size_t)(k0 + kk) * HDIM + n0 + tx];
    }
    __syncthreads();
#pragma unroll
    for (int q = 0; q < 4; ++q) {
        int nn = ty * 4 + q;
        dst[(size_t)(n0 + nn) * KTOT + koff + k0 + tx] = f2bf(tl[tx][nn]);
    }
}

// Prep: hbuf slot0=bf16(h0); bsum=bx+bh; flags+handshake scratch=0.
__global__ void prep_misc(const float* __restrict__ h0, const float* __restrict__ bx,
                          const float* __restrict__ bh, float* __restrict__ bsum,
                          unsigned short* __restrict__ hbuf, unsigned int* __restrict__ flags) {
    int idx = blockIdx.x * 256 + threadIdx.x;
    if (idx < HBUF_ELEMS) {
        hbuf[idx] = f2bf(h0[idx]);
    } else if (idx < HBUF_ELEMS + HDIM) {
        int j = idx - HBUF_ELEMS;
        bsum[j] = bx[j] + bh[j];
    } else if (idx < HBUF_ELEMS + HDIM + NFLAG + 2 * NBLK) {
        flags[idx - HBUF_ELEMS - HDIM] = 0;
    }
}

__global__ void ws_fail_kernel(float* out) { out[0] = 1.0e6f; }  // ws_size diagnostic

// ---------------------------------------------------------------------------
// R12 = R11 geometry with the spill fixed (launch_bounds 512,2 -> VGPR cap
// 256, Bf stays pinned). 64 blocks x 512 threads (8 waves). Block (g, cb)
// owns 128 output cols; wave wid owns 16. Per-thread W slice, MFMA count,
// E-store pattern IDENTICAL to R9; staging halved (seg in 0..31).
// FAN HALVED: consumer wave wid's staged cols all come from producer block
// cb_p == wid (fan-1/wave; poll = that block's 8 wave-flags, one 32B sector);
// block rendezvous couples max-of-8 producers (was max-of-16). Protocol,
// scopes, and R9 tail order (drain -> publish -> G) byte-identical.
template<bool FAST>
__device__ __forceinline__ void rnn_loop(
        const float* __restrict__ x, const unsigned short* __restrict__ WT,
        const float* __restrict__ bsum, unsigned short* __restrict__ hbuf,
        unsigned int* __restrict__ flags, float* __restrict__ out,
        unsigned short* xs, unsigned short* hs, const int tid, const int bid) {
    char* xb = (char*)xs;
    char* hb = (char*)hs;
    const int g    = bid & 7;
    const int cb   = bid >> 3;        // 0..7
    const int lane = tid & 63;
    const int wid  = tid >> 6;        // 0..7
    const int lrow = lane & 15;       // A row / C col low bits
    const int kg   = lane >> 4;       // k-group 0..3
    const int ncol = cb * CBW + wid * 16 + lrow;

    // Resident B fragments: lane holds WT[ncol][kc*32 + kg*8 .. +7]
    short8 Bf[48];
    {
        const short8* wp = (const short8*)(WT + (size_t)ncol * KTOT);
#pragma unroll
        for (int kc = 0; kc < 48; ++kc) Bf[kc] = wp[kc * 4 + kg];
    }
#pragma unroll
    for (int kc = 0; kc < 48; ++kc) asm volatile("" : "+v"(Bf[kc]));
    const float bias = bsum[ncol];

    const int sm  = tid & 15;         // staged row 0..15
    const int seg = tid >> 4;         // 1/32 of the row (32 h-cols / 16 x-cols)
    unsigned int* const myflag = &flags[(g << 6) + (cb << 3) + wid];
    // wave wid's staged cols come from producer block cb_p == wid only:
    // lane checks that block's wave-flag (lane & 7); one 32B flag sector.
    const unsigned int* const pollp =
        &flags[(g << 6) + (wid << 3) + (lane & 7)];
    const size_t rowoff = (size_t)(g * GROWS + sm) * HDIM + seg * 32;

    // ---- prologue: stage x(0) into xs buf 0 (deterministic queue: drain) ----
    {
        float4 xv0[4];
        ldx_issue(x + ((size_t)g * GROWS + sm) * IDIM + seg * 16, xv0);
        asm volatile("s_waitcnt vmcnt(0)" ::: "memory");
        __builtin_amdgcn_sched_barrier(0);
#pragma unroll
        for (int q = 0; q < 2; ++q) {
            float4 a = xv0[2 * q], b = xv0[2 * q + 1];
            ushort8 w;
            w[0] = f2bf(a.x); w[1] = f2bf(a.y); w[2] = f2bf(a.z); w[3] = f2bf(a.w);
            w[4] = f2bf(b.x); w[5] = f2bf(b.y); w[6] = f2bf(b.z); w[7] = f2bf(b.w);
            *(ushort8*)(xb + swzX(sm, seg * 32 + q * 16)) = w;
        }
        asm volatile("s_waitcnt lgkmcnt(0)" ::: "memory");
        __builtin_amdgcn_s_barrier();
        __builtin_amdgcn_sched_barrier(0);
    }

    for (int t = 0; t < T_STEPS; ++t) {
        const bool has_next = (t + 1 < T_STEPS);

        // ---- A0: per-wave fan-1 poll (producer block wid's 8 wave-flags) ----
        {
            const unsigned int tgt = (unsigned int)t;
            while (true) {
                unsigned int v = ld_u32_if(pollp);
                if (__all(v >= tgt)) break;    // no s_sleep: vmcnt RT paces the loop
            }
        }

        // ---- A: issue h(t) loads FIRST (oldest in queue), then x(t+1) ----
        ushort8 hv[4];
        ldh_issue_if(hbuf + (size_t)(t & 1) * HBUF_ELEMS + rowoff, hv);
        float4 xv[4];
        if (has_next)
            ldx_issue(x + ((size_t)(t + 1) * BATCH + g * GROWS + sm) * IDIM + seg * 16, xv);

        // ---- B: x-side MFMA (kc 0..15) under the h/x load latency ----
        const char* xcur = xb + (t & 1) * XBUFB;
        f32x4 acc0 = {0.f, 0.f, 0.f, 0.f}, acc1 = acc0, acc2 = acc0, acc3 = acc0;
#pragma unroll
        for (int kk = 0; kk < 4; ++kk) {
            short8 a0 = *(const short8*)(xcur + swzX(lrow, (4 * kk + 0) * 64 + kg * 16));
            short8 a1 = *(const short8*)(xcur + swzX(lrow, (4 * kk + 1) * 64 + kg * 16));
            short8 a2 = *(const short8*)(xcur + swzX(lrow, (4 * kk + 2) * 64 + kg * 16));
            short8 a3 = *(const short8*)(xcur + swzX(lrow, (4 * kk + 3) * 64 + kg * 16));
            acc0 = __builtin_amdgcn_mfma_f32_16x16x32_bf16(a0, Bf[4 * kk + 0], acc0, 0, 0, 0);
            acc1 = __builtin_amdgcn_mfma_f32_16x16x32_bf16(a1, Bf[4 * kk + 1], acc1, 0, 0, 0);
            acc2 = __builtin_amdgcn_mfma_f32_16x16x32_bf16(a2, Bf[4 * kk + 2], acc2, 0, 0, 0);
            acc3 = __builtin_amdgcn_mfma_f32_16x16x32_bf16(a3, Bf[4 * kk + 3], acc3, 0, 0, 0);
        }

        // ---- C: counted wait = h loads done (4 x-loads keep flying) ----
        if (has_next) asm volatile("s_waitcnt vmcnt(4)" ::: "memory");
        else          asm volatile("s_waitcnt vmcnt(0)" ::: "memory");
        __builtin_amdgcn_sched_barrier(0);
#pragma unroll
        for (int q = 0; q < 4; ++q)
            *(ushort8*)(hb + swzH(sm, seg * 64 + q * 16)) = hv[q];
        asm volatile("s_waitcnt lgkmcnt(0)" ::: "memory");
        __builtin_amdgcn_s_barrier();          // raw: no auto vmcnt(0) drain
        __builtin_amdgcn_sched_barrier(0);

        // ---- D: h-side MFMA (kc 16..47) ----
#pragma unroll
        for (int kk = 4; kk < 12; ++kk) {
            short8 a0 = *(const short8*)(hb + swzH(lrow, (4 * kk - 16 + 0) * 64 + kg * 16));
            short8 a1 = *(const short8*)(hb + swzH(lrow, (4 * kk - 16 + 1) * 64 + kg * 16));
            short8 a2 = *(const short8*)(hb + swzH(lrow, (4 * kk - 16 + 2) * 64 + kg * 16));
            short8 a3 = *(const short8*)(hb + swzH(lrow, (4 * kk - 16 + 3) * 64 + kg * 16));
            acc0 = __builtin_amdgcn_mfma_f32_16x16x32_bf16(a0, Bf[4 * kk + 0], acc0, 0, 0, 0);
            acc1 = __builtin_amdgcn_mfma_f32_16x16x32_bf16(a1, Bf[4 * kk + 1], acc1, 0, 0, 0);
            acc2 = __builtin_amdgcn_mfma_f32_16x16x32_bf16(a2, Bf[4 * kk + 2], acc2, 0, 0, 0);
            acc3 = __builtin_amdgcn_mfma_f32_16x16x32_bf16(a3, Bf[4 * kk + 3], acc3, 0, 0, 0);
        }

        // ---- E: epilogue. C row = kg*4 + r, col = ncol (R0 store layout:
        // quarter-wave lanes write 32B-contiguous runs; R6 proved C^T worse) ----
        if (!has_next) {
#pragma unroll
            for (int r = 0; r < 4; ++r) {
                float pre = acc0[r] + acc1[r] + acc2[r] + acc3[r] + bias;
                out[(size_t)(g * GROWS + kg * 4 + r) * HDIM + ncol] = fast_tanh(pre);
            }
            break;
        }
        {
            unsigned short* hdst = hbuf + (size_t)((t + 1) & 1) * HBUF_ELEMS;
#pragma unroll
            for (int r = 0; r < 4; ++r) {
                float pre = acc0[r] + acc1[r] + acc2[r] + acc3[r] + bias;
                float hvf = fast_tanh(pre);
                st_h16_c<FAST>(hdst + (size_t)(g * GROWS + kg * 4 + r) * HDIM + ncol, f2bf(hvf));
            }
        }

        // ---- F: drain (L2 acks) then publish IMMEDIATELY (R10 lesson:
        // nothing goes between drain and publish) ----
        asm volatile("s_waitcnt vmcnt(0)" ::: "memory");
        __builtin_amdgcn_sched_barrier(0);
        if (lane == 0) st_u32_c<FAST>(myflag, (unsigned int)(t + 1));

        // ---- G: stage x(t+1) regs -> xs[(t+1)&1] (no waits) ----
        {
            char* xnxt = xb + ((t + 1) & 1) * XBUFB;
#pragma unroll
            for (int q = 0; q < 2; ++q) {
                float4 a = xv[2 * q], b = xv[2 * q + 1];
                ushort8 w;
                w[0] = f2bf(a.x); w[1] = f2bf(a.y); w[2] = f2bf(a.z); w[3] = f2bf(a.w);
                w[4] = f2bf(b.x); w[5] = f2bf(b.y); w[6] = f2bf(b.z); w[7] = f2bf(b.w);
                *(ushort8*)(xnxt + swzX(sm, seg * 32 + q * 16)) = w;
            }
        }

        // ---- loop end: hs/xs reuse guard ----
        asm volatile("s_waitcnt lgkmcnt(0)" ::: "memory");
        __builtin_amdgcn_s_barrier();
        __builtin_amdgcn_sched_barrier(0);
    }
}

// ---------------------------------------------------------------------------
// Handshake (completed on HW, R8/R9/R11): exchange HW_REG_XCC_ID via the
// proven sc0 sc1 path; all 64 blocks co-resident. Same-XCD group -> FAST
// (plain h + flag stores, L2-ack drains); else all-sc0sc1 SLOW path.
// launch_bounds(512,2): 8-wave block = 2 waves/SIMD -> VGPR cap 256, Bf
// (192 VGPRs) stays pinned (R11 lesson: (512,1) capped at 128 and spilled).
__global__ __launch_bounds__(512, 2) void rnn_fused(
        const float* __restrict__ x, const unsigned short* __restrict__ WT,
        const float* __restrict__ bsum, unsigned short* __restrict__ hbuf,
        unsigned int* __restrict__ flags, float* __restrict__ out) {
    __shared__ unsigned short xs[2 * GROWS * IDIM];   // 32 KB (double-buffered x tile)
    __shared__ unsigned short hs[GROWS * HDIM];       // 32 KB (h tile)
    const int tid  = threadIdx.x;
    const int bid  = blockIdx.x;
    const int g    = bid & 7;
    const int lane = tid & 63;

    unsigned int myxcd;
    asm volatile("s_getreg_b32 %0, hwreg(HW_REG_XCC_ID)" : "=s"(myxcd));
    unsigned int* const xcdmap = flags + NFLAG;          // [NBLK]
    unsigned int* const hsflag = flags + NFLAG + NBLK;   // [NBLK]
    if (tid == 0) {
        st_u32_if(&xcdmap[bid], myxcd + 1u);
        asm volatile("s_waitcnt vmcnt(0)" ::: "memory");
        st_u32_if(&hsflag[bid], 1u);
    }
    // peers of group g are bids g, g+8, ..., g+56; lanes 8..63 duplicate
    const int peer = g + 8 * (lane & 7);
    while (true) {
        unsigned int v = ld_u32_if(&hsflag[peer]);
        if (__all(v != 0)) break;
    }
    const unsigned int px = ld_u32_if(&xcdmap[peer]);
    // verdict symmetric across the group (same 8 values) -> same path chosen
    if (__all(px == myxcd + 1u))
        rnn_loop<true >(x, WT, bsum, hbuf, flags, out, xs, hs, tid, bid);
    else
        rnn_loop<false>(x, WT, bsum, hbuf, flags, out, xs, hs, tid, bid);
}

// ---------------------------------------------------------------------------
extern "C" void kernel_launch(void* const* d_in, const int* in_sizes, int n_in,
                              void* d_out, int out_size, void* d_ws, size_t ws_size,
                              hipStream_t stream) {
    const float* x  = (const float*)d_in[0];
    const float* h0 = (const float*)d_in[1];
    const float* Wx = (const float*)d_in[2];
    const float* bx = (const float*)d_in[3];
    const float* Wh = (const float*)d_in[4];
    const float* bh = (const float*)d_in[5];
    float* out = (float*)d_out;

    // workspace layout (128B-aligned pieces)
    const size_t OFF_WT = 0;                    // 1024*1536 bf16 = 3,145,728 B
    const size_t OFF_BS = 3145728;              // 1024 f32 = 4096 B
    const size_t OFF_HB = 3149824;              // 2*128*1024 bf16 = 524,288 B
    const size_t OFF_FL = 3674112;              // (512 + 128) u32 = 2560 B
    const size_t WS_NEED = 3676672;
    if (ws_size < WS_NEED) {                    // diagnostic: absmax ~1e6 => ws too small
        hipLaunchKernelGGL(ws_fail_kernel, dim3(1), dim3(1), 0, stream, out);
        return;
    }

    unsigned short* WT    = (unsigned short*)((char*)d_ws + OFF_WT);
    float*          bsum  = (float*)((char*)d_ws + OFF_BS);
    unsigned short* hbuf  = (unsigned short*)((char*)d_ws + OFF_HB);
    unsigned int*   flags = (unsigned int*)((char*)d_ws + OFF_FL);

    prep_transpose<<<dim3(IDIM / 32, HDIM / 32), dim3(32, 8), 0, stream>>>(Wx, WT, 0);
    prep_transpose<<<dim3(HDIM / 32, HDIM / 32), dim3(32, 8), 0, stream>>>(Wh, WT, IDIM);
    const int misc_total = HBUF_ELEMS + HDIM + NFLAG + 2 * NBLK;
    prep_misc<<<dim3((misc_total + 255) / 256), dim3(256), 0, stream>>>(
        h0, bx, bh, bsum, hbuf, flags);
    rnn_fused<<<dim3(NBLK), dim3(512), 0, stream>>>(
        x, WT, bsum, hbuf, flags, out);
}

// Round 13
// 3413.597 us; speedup vs baseline: 1.0013x; 1.0013x over previous
//
#include <hip/hip_runtime.h>
#include <hip/hip_bf16.h>

typedef __attribute__((ext_vector_type(4))) float f32x4;
typedef __attribute__((ext_vector_type(8))) short short8;
typedef __attribute__((ext_vector_type(8))) unsigned short ushort8;

#define T_STEPS 512
#define BATCH   128
#define IDIM    512
#define HDIM    1024
#define KTOT    1536           // IDIM + HDIM (fused [x_t | h] @ [Wx; Wh])
#define NGROUP  8              // batch groups (16 rows each)
#define GROWS   16             // batch rows per group
#define NCB     8              // column-blocks per group (128 cols each)
#define CBW     128            // output columns per block (8 waves x 16)
#define NBLK    (NGROUP * NCB) // 64 blocks
#define HBUF_ELEMS (BATCH * HDIM)
#define XBUFB   (GROWS * IDIM * 2)   // bytes per xs half
#define NFLAG   (NGROUP * 64)        // per-WAVE flags (8 blocks x 8 waves per group)
// handshake scratch appended after flags: xcdmap[NBLK], hsflag[NBLK]

// f32 -> bf16 round-to-nearest-even
__device__ __forceinline__ unsigned short f2bf(float f) {
    unsigned int u = __builtin_bit_cast(unsigned int, f);
    u = (u + 0x7FFFu + ((u >> 16) & 1u)) >> 16;
    return (unsigned short)u;
}

// fast tanh: clamp +-9, e2x = exp2(2*log2e*x), (e2x-1)*rcp(e2x+1).
__device__ __forceinline__ float fast_tanh(float x) {
    x = fminf(9.0f, fmaxf(-9.0f, x));
    float t = __builtin_exp2f(x * 2.8853900817779268f);
    return (t - 1.0f) * __builtin_amdgcn_rcpf(t + 1.0f);
}

// XOR swizzles (row strides 0 mod 128B; XOR row low-bits into the 16B-slot index)
__device__ __forceinline__ int swzX(int row, int c) { return row * 1024 + (c ^ ((row & 7) << 4)); }
__device__ __forceinline__ int swzH(int row, int c) { return row * 2048 + (c ^ ((row & 7) << 4)); }

// ---- coherence primitives ---------------------------------------------------
// Session model (validated R8+R9): sc0 sc1 STORES write through to HBM and
// their vmcnt ack costs ~1100cy; PLAIN stores ack at the shared same-XCD L2
// (~250cy) and sc0 sc1 (L1-bypassing) consumer loads dirty-hit that line.
// R8: h-data plain (WRITE 139.5->9.2MB, -182us). R9: flag publish plain
// (WRITE ->1MB, -387us). R10: NEVER put work between drain and publish.
// R11/R12 LESSON: the VGPR allocator targets 4 waves/SIMD (128 VGPR) for
// 512-thread blocks REGARDLESS of launch_bounds' min-waves arg, spilling the
// pinned Bf (8.2MB WRITE spill signature). Forcing needs
// amdgpu_waves_per_eu(2,2) — exact pin, no occupancy incentive left.
__device__ __forceinline__ void st_u32_if(unsigned int* p, unsigned int v) {
    asm volatile("global_store_dword %0, %1, off sc0 sc1" :: "v"(p), "v"(v) : "memory");
}
template<bool FAST>
__device__ __forceinline__ void st_u32_c(unsigned int* p, unsigned int v) {
    if (FAST) asm volatile("global_store_dword %0, %1, off" :: "v"(p), "v"(v) : "memory");
    else      asm volatile("global_store_dword %0, %1, off sc0 sc1" :: "v"(p), "v"(v) : "memory");
}
template<bool FAST>
__device__ __forceinline__ void st_h16_c(unsigned short* p, unsigned short v) {
    if (FAST) asm volatile("global_store_short %0, %1, off" :: "v"(p), "v"(v) : "memory");
    else      asm volatile("global_store_short %0, %1, off sc0 sc1" :: "v"(p), "v"(v) : "memory");
}
__device__ __forceinline__ unsigned int ld_u32_if(const unsigned int* p) {
    unsigned int v;
    asm volatile("global_load_dword %0, %1, off sc0 sc1\n\ts_waitcnt vmcnt(0)"
                 : "=v"(v) : "v"(p) : "memory");
    return v;
}
// issue 4 pipelined dwordx4 h-slice loads (64 B), NO wait (counted vmcnt)
__device__ __forceinline__ void ldh_issue_if(const unsigned short* p, ushort8 v[4]) {
    asm volatile(
        "global_load_dwordx4 %0, %4, off sc0 sc1\n\t"
        "global_load_dwordx4 %1, %4, off offset:16 sc0 sc1\n\t"
        "global_load_dwordx4 %2, %4, off offset:32 sc0 sc1\n\t"
        "global_load_dwordx4 %3, %4, off offset:48 sc0 sc1"
        : "=&v"(v[0]), "=&v"(v[1]), "=&v"(v[2]), "=&v"(v[3])
        : "v"(p) : "memory");
}
// issue 4 pipelined dwordx4 x-slice loads (64 B of f32), normal caching, NO wait
__device__ __forceinline__ void ldx_issue(const float* p, float4 v[4]) {
    asm volatile(
        "global_load_dwordx4 %0, %4, off\n\t"
        "global_load_dwordx4 %1, %4, off offset:16\n\t"
        "global_load_dwordx4 %2, %4, off offset:32\n\t"
        "global_load_dwordx4 %3, %4, off offset:48"
        : "=&v"(v[0]), "=&v"(v[1]), "=&v"(v[2]), "=&v"(v[3])
        : "v"(p) : "memory");
}

// ---------------------------------------------------------------------------
// Prep: WT[n][k] = bf16(W[k][n]) for W in {Wx (koff=0), Wh (koff=IDIM)}.
__global__ void prep_transpose(const float* __restrict__ src,
                               unsigned short* __restrict__ dst, int koff) {
    __shared__ float tl[32][33];
    const int tx = threadIdx.x, ty = threadIdx.y;
    const int k0 = blockIdx.x * 32, n0 = blockIdx.y * 32;
#pragma unroll
    for (int q = 0; q < 4; ++q) {
        int kk = ty * 4 + q;
        tl[kk][tx] = src[(size_t)(k0 + kk) * HDIM + n0 + tx];
    }
    __syncthreads();
#pragma unroll
    for (int q = 0; q < 4; ++q) {
        int nn = ty * 4 + q;
        dst[(size_t)(n0 + nn) * KTOT + koff + k0 + tx] = f2bf(tl[tx][nn]);
    }
}

// Prep: hbuf slot0=bf16(h0); bsum=bx+bh; flags+handshake scratch=0.
__global__ void prep_misc(const float* __restrict__ h0, const float* __restrict__ bx,
                          const float* __restrict__ bh, float* __restrict__ bsum,
                          unsigned short* __restrict__ hbuf, unsigned int* __restrict__ flags) {
    int idx = blockIdx.x * 256 + threadIdx.x;
    if (idx < HBUF_ELEMS) {
        hbuf[idx] = f2bf(h0[idx]);
    } else if (idx < HBUF_ELEMS + HDIM) {
        int j = idx - HBUF_ELEMS;
        bsum[j] = bx[j] + bh[j];
    } else if (idx < HBUF_ELEMS + HDIM + NFLAG + 2 * NBLK) {
        flags[idx - HBUF_ELEMS - HDIM] = 0;
    }
}

__global__ void ws_fail_kernel(float* out) { out[0] = 1.0e6f; }  // ws_size diagnostic

// ---------------------------------------------------------------------------
// R13 = R12 with the VGPR cap forced via amdgpu_waves_per_eu(2,2).
// 64 blocks x 512 threads (8 waves; each block alone on its CU = exactly
// 2 waves/SIMD, matching the pin). Per-thread W slice, MFMA count, E-store
// pattern IDENTICAL to R9; staging halved (seg in 0..31).
// FAN HALVED: consumer wave wid's staged cols all come from producer block
// cb_p == wid (fan-1/wave; poll = that block's 8 wave-flags, one 32B sector);
// block rendezvous couples max-of-8 producers (was max-of-16). Protocol,
// scopes, and R9 tail order (drain -> publish -> G) byte-identical.
template<bool FAST>
__device__ __forceinline__ void rnn_loop(
        const float* __restrict__ x, const unsigned short* __restrict__ WT,
        const float* __restrict__ bsum, unsigned short* __restrict__ hbuf,
        unsigned int* __restrict__ flags, float* __restrict__ out,
        unsigned short* xs, unsigned short* hs, const int tid, const int bid) {
    char* xb = (char*)xs;
    char* hb = (char*)hs;
    const int g    = bid & 7;
    const int cb   = bid >> 3;        // 0..7
    const int lane = tid & 63;
    const int wid  = tid >> 6;        // 0..7
    const int lrow = lane & 15;       // A row / C col low bits
    const int kg   = lane >> 4;       // k-group 0..3
    const int ncol = cb * CBW + wid * 16 + lrow;

    // Resident B fragments: lane holds WT[ncol][kc*32 + kg*8 .. +7]
    short8 Bf[48];
    {
        const short8* wp = (const short8*)(WT + (size_t)ncol * KTOT);
#pragma unroll
        for (int kc = 0; kc < 48; ++kc) Bf[kc] = wp[kc * 4 + kg];
    }
#pragma unroll
    for (int kc = 0; kc < 48; ++kc) asm volatile("" : "+v"(Bf[kc]));
    const float bias = bsum[ncol];

    const int sm  = tid & 15;         // staged row 0..15
    const int seg = tid >> 4;         // 1/32 of the row (32 h-cols / 16 x-cols)
    unsigned int* const myflag = &flags[(g << 6) + (cb << 3) + wid];
    // wave wid's staged cols come from producer block cb_p == wid only:
    // lane checks that block's wave-flag (lane & 7); one 32B flag sector.
    const unsigned int* const pollp =
        &flags[(g << 6) + (wid << 3) + (lane & 7)];
    const size_t rowoff = (size_t)(g * GROWS + sm) * HDIM + seg * 32;

    // ---- prologue: stage x(0) into xs buf 0 (deterministic queue: drain) ----
    {
        float4 xv0[4];
        ldx_issue(x + ((size_t)g * GROWS + sm) * IDIM + seg * 16, xv0);
        asm volatile("s_waitcnt vmcnt(0)" ::: "memory");
        __builtin_amdgcn_sched_barrier(0);
#pragma unroll
        for (int q = 0; q < 2; ++q) {
            float4 a = xv0[2 * q], b = xv0[2 * q + 1];
            ushort8 w;
            w[0] = f2bf(a.x); w[1] = f2bf(a.y); w[2] = f2bf(a.z); w[3] = f2bf(a.w);
            w[4] = f2bf(b.x); w[5] = f2bf(b.y); w[6] = f2bf(b.z); w[7] = f2bf(b.w);
            *(ushort8*)(xb + swzX(sm, seg * 32 + q * 16)) = w;
        }
        asm volatile("s_waitcnt lgkmcnt(0)" ::: "memory");
        __builtin_amdgcn_s_barrier();
        __builtin_amdgcn_sched_barrier(0);
    }

    for (int t = 0; t < T_STEPS; ++t) {
        const bool has_next = (t + 1 < T_STEPS);

        // ---- A0: per-wave fan-1 poll (producer block wid's 8 wave-flags) ----
        {
            const unsigned int tgt = (unsigned int)t;
            while (true) {
                unsigned int v = ld_u32_if(pollp);
                if (__all(v >= tgt)) break;    // no s_sleep: vmcnt RT paces the loop
            }
        }

        // ---- A: issue h(t) loads FIRST (oldest in queue), then x(t+1) ----
        ushort8 hv[4];
        ldh_issue_if(hbuf + (size_t)(t & 1) * HBUF_ELEMS + rowoff, hv);
        float4 xv[4];
        if (has_next)
            ldx_issue(x + ((size_t)(t + 1) * BATCH + g * GROWS + sm) * IDIM + seg * 16, xv);

        // ---- B: x-side MFMA (kc 0..15) under the h/x load latency ----
        const char* xcur = xb + (t & 1) * XBUFB;
        f32x4 acc0 = {0.f, 0.f, 0.f, 0.f}, acc1 = acc0, acc2 = acc0, acc3 = acc0;
#pragma unroll
        for (int kk = 0; kk < 4; ++kk) {
            short8 a0 = *(const short8*)(xcur + swzX(lrow, (4 * kk + 0) * 64 + kg * 16));
            short8 a1 = *(const short8*)(xcur + swzX(lrow, (4 * kk + 1) * 64 + kg * 16));
            short8 a2 = *(const short8*)(xcur + swzX(lrow, (4 * kk + 2) * 64 + kg * 16));
            short8 a3 = *(const short8*)(xcur + swzX(lrow, (4 * kk + 3) * 64 + kg * 16));
            acc0 = __builtin_amdgcn_mfma_f32_16x16x32_bf16(a0, Bf[4 * kk + 0], acc0, 0, 0, 0);
            acc1 = __builtin_amdgcn_mfma_f32_16x16x32_bf16(a1, Bf[4 * kk + 1], acc1, 0, 0, 0);
            acc2 = __builtin_amdgcn_mfma_f32_16x16x32_bf16(a2, Bf[4 * kk + 2], acc2, 0, 0, 0);
            acc3 = __builtin_amdgcn_mfma_f32_16x16x32_bf16(a3, Bf[4 * kk + 3], acc3, 0, 0, 0);
        }

        // ---- C: counted wait = h loads done (4 x-loads keep flying) ----
        if (has_next) asm volatile("s_waitcnt vmcnt(4)" ::: "memory");
        else          asm volatile("s_waitcnt vmcnt(0)" ::: "memory");
        __builtin_amdgcn_sched_barrier(0);
#pragma unroll
        for (int q = 0; q < 4; ++q)
            *(ushort8*)(hb + swzH(sm, seg * 64 + q * 16)) = hv[q];
        asm volatile("s_waitcnt lgkmcnt(0)" ::: "memory");
        __builtin_amdgcn_s_barrier();          // raw: no auto vmcnt(0) drain
        __builtin_amdgcn_sched_barrier(0);

        // ---- D: h-side MFMA (kc 16..47) ----
#pragma unroll
        for (int kk = 4; kk < 12; ++kk) {
            short8 a0 = *(const short8*)(hb + swzH(lrow, (4 * kk - 16 + 0) * 64 + kg * 16));
            short8 a1 = *(const short8*)(hb + swzH(lrow, (4 * kk - 16 + 1) * 64 + kg * 16));
            short8 a2 = *(const short8*)(hb + swzH(lrow, (4 * kk - 16 + 2) * 64 + kg * 16));
            short8 a3 = *(const short8*)(hb + swzH(lrow, (4 * kk - 16 + 3) * 64 + kg * 16));
            acc0 = __builtin_amdgcn_mfma_f32_16x16x32_bf16(a0, Bf[4 * kk + 0], acc0, 0, 0, 0);
            acc1 = __builtin_amdgcn_mfma_f32_16x16x32_bf16(a1, Bf[4 * kk + 1], acc1, 0, 0, 0);
            acc2 = __builtin_amdgcn_mfma_f32_16x16x32_bf16(a2, Bf[4 * kk + 2], acc2, 0, 0, 0);
            acc3 = __builtin_amdgcn_mfma_f32_16x16x32_bf16(a3, Bf[4 * kk + 3], acc3, 0, 0, 0);
        }

        // ---- E: epilogue. C row = kg*4 + r, col = ncol (R0 store layout:
        // quarter-wave lanes write 32B-contiguous runs; R6 proved C^T worse) ----
        if (!has_next) {
#pragma unroll
            for (int r = 0; r < 4; ++r) {
                float pre = acc0[r] + acc1[r] + acc2[r] + acc3[r] + bias;
                out[(size_t)(g * GROWS + kg * 4 + r) * HDIM + ncol] = fast_tanh(pre);
            }
            break;
        }
        {
            unsigned short* hdst = hbuf + (size_t)((t + 1) & 1) * HBUF_ELEMS;
#pragma unroll
            for (int r = 0; r < 4; ++r) {
                float pre = acc0[r] + acc1[r] + acc2[r] + acc3[r] + bias;
                float hvf = fast_tanh(pre);
                st_h16_c<FAST>(hdst + (size_t)(g * GROWS + kg * 4 + r) * HDIM + ncol, f2bf(hvf));
            }
        }

        // ---- F: drain (L2 acks) then publish IMMEDIATELY (R10 lesson:
        // nothing goes between drain and publish) ----
        asm volatile("s_waitcnt vmcnt(0)" ::: "memory");
        __builtin_amdgcn_sched_barrier(0);
        if (lane == 0) st_u32_c<FAST>(myflag, (unsigned int)(t + 1));

        // ---- G: stage x(t+1) regs -> xs[(t+1)&1] (no waits) ----
        {
            char* xnxt = xb + ((t + 1) & 1) * XBUFB;
#pragma unroll
            for (int q = 0; q < 2; ++q) {
                float4 a = xv[2 * q], b = xv[2 * q + 1];
                ushort8 w;
                w[0] = f2bf(a.x); w[1] = f2bf(a.y); w[2] = f2bf(a.z); w[3] = f2bf(a.w);
                w[4] = f2bf(b.x); w[5] = f2bf(b.y); w[6] = f2bf(b.z); w[7] = f2bf(b.w);
                *(ushort8*)(xnxt + swzX(sm, seg * 32 + q * 16)) = w;
            }
        }

        // ---- loop end: hs/xs reuse guard ----
        asm volatile("s_waitcnt lgkmcnt(0)" ::: "memory");
        __builtin_amdgcn_s_barrier();
        __builtin_amdgcn_sched_barrier(0);
    }
}

// ---------------------------------------------------------------------------
// Handshake (completed on HW, R8/R9/R11): exchange HW_REG_XCC_ID via the
// proven sc0 sc1 path; all 64 blocks co-resident. Same-XCD group -> FAST
// (plain h + flag stores, L2-ack drains); else all-sc0sc1 SLOW path.
// amdgpu_waves_per_eu(2,2): exact pin -> VGPR budget 256/wave, no occupancy
// incentive for the allocator to shrink to 128 and spill Bf (R11/R12 lesson:
// launch_bounds' min-waves arg does NOT prevent the 4-wave heuristic).
__global__ __attribute__((amdgpu_flat_work_group_size(512, 512),
                          amdgpu_waves_per_eu(2, 2)))
void rnn_fused(
        const float* __restrict__ x, const unsigned short* __restrict__ WT,
        const float* __restrict__ bsum, unsigned short* __restrict__ hbuf,
        unsigned int* __restrict__ flags, float* __restrict__ out) {
    __shared__ unsigned short xs[2 * GROWS * IDIM];   // 32 KB (double-buffered x tile)
    __shared__ unsigned short hs[GROWS * HDIM];       // 32 KB (h tile)
    const int tid  = threadIdx.x;
    const int bid  = blockIdx.x;
    const int g    = bid & 7;
    const int lane = tid & 63;

    unsigned int myxcd;
    asm volatile("s_getreg_b32 %0, hwreg(HW_REG_XCC_ID)" : "=s"(myxcd));
    unsigned int* const xcdmap = flags + NFLAG;          // [NBLK]
    unsigned int* const hsflag = flags + NFLAG + NBLK;   // [NBLK]
    if (tid == 0) {
        st_u32_if(&xcdmap[bid], myxcd + 1u);
        asm volatile("s_waitcnt vmcnt(0)" ::: "memory");
        st_u32_if(&hsflag[bid], 1u);
    }
    // peers of group g are bids g, g+8, ..., g+56; lanes 8..63 duplicate
    const int peer = g + 8 * (lane & 7);
    while (true) {
        unsigned int v = ld_u32_if(&hsflag[peer]);
        if (__all(v != 0)) break;
    }
    const unsigned int px = ld_u32_if(&xcdmap[peer]);
    // verdict symmetric across the group (same 8 values) -> same path chosen
    if (__all(px == myxcd + 1u))
        rnn_loop<true >(x, WT, bsum, hbuf, flags, out, xs, hs, tid, bid);
    else
        rnn_loop<false>(x, WT, bsum, hbuf, flags, out, xs, hs, tid, bid);
}

// ---------------------------------------------------------------------------
extern "C" void kernel_launch(void* const* d_in, const int* in_sizes, int n_in,
                              void* d_out, int out_size, void* d_ws, size_t ws_size,
                              hipStream_t stream) {
    const float* x  = (const float*)d_in[0];
    const float* h0 = (const float*)d_in[1];
    const float* Wx = (const float*)d_in[2];
    const float* bx = (const float*)d_in[3];
    const float* Wh = (const float*)d_in[4];
    const float* bh = (const float*)d_in[5];
    float* out = (float*)d_out;

    // workspace layout (128B-aligned pieces)
    const size_t OFF_WT = 0;                    // 1024*1536 bf16 = 3,145,728 B
    const size_t OFF_BS = 3145728;              // 1024 f32 = 4096 B
    const size_t OFF_HB = 3149824;              // 2*128*1024 bf16 = 524,288 B
    const size_t OFF_FL = 3674112;              // (512 + 128) u32 = 2560 B
    const size_t WS_NEED = 3676672;
    if (ws_size < WS_NEED) {                    // diagnostic: absmax ~1e6 => ws too small
        hipLaunchKernelGGL(ws_fail_kernel, dim3(1), dim3(1), 0, stream, out);
        return;
    }

    unsigned short* WT    = (unsigned short*)((char*)d_ws + OFF_WT);
    float*          bsum  = (float*)((char*)d_ws + OFF_BS);
    unsigned short* hbuf  = (unsigned short*)((char*)d_ws + OFF_HB);
    unsigned int*   flags = (unsigned int*)((char*)d_ws + OFF_FL);

    prep_transpose<<<dim3(IDIM / 32, HDIM / 32), dim3(32, 8), 0, stream>>>(Wx, WT, 0);
    prep_transpose<<<dim3(HDIM / 32, HDIM / 32), dim3(32, 8), 0, stream>>>(Wh, WT, IDIM);
    const int misc_total = HBUF_ELEMS + HDIM + NFLAG + 2 * NBLK;
    prep_misc<<<dim3((misc_total + 255) / 256), dim3(256), 0, stream>>>(
        h0, bx, bh, bsum, hbuf, flags);
    rnn_fused<<<dim3(NBLK), dim3(512), 0, stream>>>(
        x, WT, bsum, hbuf, flags, out);
}

// Round 14
// 1635.016 us; speedup vs baseline: 2.0905x; 2.0878x over previous
//
#include <hip/hip_runtime.h>
#include <hip/hip_bf16.h>

typedef __attribute__((ext_vector_type(4))) float f32x4;
typedef __attribute__((ext_vector_type(8))) short short8;
typedef __attribute__((ext_vector_type(8))) unsigned short ushort8;

#define T_STEPS 512
#define BATCH   128
#define IDIM    512
#define HDIM    1024
#define KTOT    1536           // IDIM + HDIM (fused [x_t | h] @ [Wx; Wh])
#define NGROUP  8              // batch groups (16 rows each)
#define GROWS   16             // batch rows per group
#define NCB     16             // column-blocks per group
#define CBW     64             // output columns per block (4 waves x 16)
#define NBLK    (NGROUP * NCB) // 128 blocks
#define HBUF_ELEMS (BATCH * HDIM)
#define XBUFB   (GROWS * IDIM * 2)   // bytes per xs half
#define NFLAG   (NGROUP * 64)        // per-WAVE flags, packed 4B (coalesced polls)
// handshake scratch appended after flags: xcdmap[NBLK], hsflag[NBLK]

// f32 -> bf16 round-to-nearest-even
__device__ __forceinline__ unsigned short f2bf(float f) {
    unsigned int u = __builtin_bit_cast(unsigned int, f);
    u = (u + 0x7FFFu + ((u >> 16) & 1u)) >> 16;
    return (unsigned short)u;
}

// fast tanh: clamp +-9, e2x = exp2(2*log2e*x), (e2x-1)*rcp(e2x+1).
__device__ __forceinline__ float fast_tanh(float x) {
    x = fminf(9.0f, fmaxf(-9.0f, x));
    float t = __builtin_exp2f(x * 2.8853900817779268f);
    return (t - 1.0f) * __builtin_amdgcn_rcpf(t + 1.0f);
}

// XOR swizzles (row strides 0 mod 128B; XOR row low-bits into the 16B-slot index)
__device__ __forceinline__ int swzX(int row, int c) { return row * 1024 + (c ^ ((row & 7) << 4)); }
__device__ __forceinline__ int swzH(int row, int c) { return row * 2048 + (c ^ ((row & 7) << 4)); }

// ---- coherence primitives ---------------------------------------------------
// Session model (validated R8+R9): sc0 sc1 STORES write through to HBM and
// their vmcnt ack costs ~1100cy; PLAIN stores ack at the shared same-XCD L2
// (~250cy) and sc0 sc1 (L1-bypassing) consumer loads dirty-hit that line.
// R8: h-data plain (WRITE 139.5->9.2MB, -182us). R9: flag publish plain
// (WRITE ->1MB, -387us). R10: NEVER put work between drain and publish.
// R11-R13: 512-thread geometry is tool-blocked (allocator pins 128 VGPR and
// spills Bf regardless of launch_bounds / waves_per_eu forcing) — abandoned.
// R14: poll-load ISSUE hoisted to right after the publish — its L2 RT
// overlaps G-staging + loop-end barrier; monotone flags make stale early
// reads fail-safe (retry), steady-state poll traffic unchanged (1 load/step).
__device__ __forceinline__ void st_u32_if(unsigned int* p, unsigned int v) {
    asm volatile("global_store_dword %0, %1, off sc0 sc1" :: "v"(p), "v"(v) : "memory");
}
template<bool FAST>
__device__ __forceinline__ void st_u32_c(unsigned int* p, unsigned int v) {
    if (FAST) asm volatile("global_store_dword %0, %1, off" :: "v"(p), "v"(v) : "memory");
    else      asm volatile("global_store_dword %0, %1, off sc0 sc1" :: "v"(p), "v"(v) : "memory");
}
template<bool FAST>
__device__ __forceinline__ void st_h16_c(unsigned short* p, unsigned short v) {
    if (FAST) asm volatile("global_store_short %0, %1, off" :: "v"(p), "v"(v) : "memory");
    else      asm volatile("global_store_short %0, %1, off sc0 sc1" :: "v"(p), "v"(v) : "memory");
}
__device__ __forceinline__ unsigned int ld_u32_if(const unsigned int* p) {
    unsigned int v;
    asm volatile("global_load_dword %0, %1, off sc0 sc1\n\ts_waitcnt vmcnt(0)"
                 : "=v"(v) : "v"(p) : "memory");
    return v;
}
// issue the poll load WITHOUT waiting (consumed after a later vmcnt(0))
__device__ __forceinline__ unsigned int ld_u32_issue_if(const unsigned int* p) {
    unsigned int v;
    asm volatile("global_load_dword %0, %1, off sc0 sc1"
                 : "=v"(v) : "v"(p) : "memory");
    return v;
}
// issue 8 pipelined dwordx4 h-tile loads (128 B), NO wait (drained by counted vmcnt)
__device__ __forceinline__ void ldh_issue_if(const unsigned short* p, ushort8 v[8]) {
    asm volatile(
        "global_load_dwordx4 %0, %8, off sc0 sc1\n\t"
        "global_load_dwordx4 %1, %8, off offset:16 sc0 sc1\n\t"
        "global_load_dwordx4 %2, %8, off offset:32 sc0 sc1\n\t"
        "global_load_dwordx4 %3, %8, off offset:48 sc0 sc1\n\t"
        "global_load_dwordx4 %4, %8, off offset:64 sc0 sc1\n\t"
        "global_load_dwordx4 %5, %8, off offset:80 sc0 sc1\n\t"
        "global_load_dwordx4 %6, %8, off offset:96 sc0 sc1\n\t"
        "global_load_dwordx4 %7, %8, off offset:112 sc0 sc1"
        : "=&v"(v[0]), "=&v"(v[1]), "=&v"(v[2]), "=&v"(v[3]),
          "=&v"(v[4]), "=&v"(v[5]), "=&v"(v[6]), "=&v"(v[7])
        : "v"(p) : "memory");
}
// issue 8 pipelined dwordx4 x-tile loads (128 B of f32), normal caching, NO wait
__device__ __forceinline__ void ldx_issue(const float* p, float4 v[8]) {
    asm volatile(
        "global_load_dwordx4 %0, %8, off\n\t"
        "global_load_dwordx4 %1, %8, off offset:16\n\t"
        "global_load_dwordx4 %2, %8, off offset:32\n\t"
        "global_load_dwordx4 %3, %8, off offset:48\n\t"
        "global_load_dwordx4 %4, %8, off offset:64\n\t"
        "global_load_dwordx4 %5, %8, off offset:80\n\t"
        "global_load_dwordx4 %6, %8, off offset:96\n\t"
        "global_load_dwordx4 %7, %8, off offset:112"
        : "=&v"(v[0]), "=&v"(v[1]), "=&v"(v[2]), "=&v"(v[3]),
          "=&v"(v[4]), "=&v"(v[5]), "=&v"(v[6]), "=&v"(v[7])
        : "v"(p) : "memory");
}

// ---------------------------------------------------------------------------
// Prep: WT[n][k] = bf16(W[k][n]) for W in {Wx (koff=0), Wh (koff=IDIM)}.
__global__ void prep_transpose(const float* __restrict__ src,
                               unsigned short* __restrict__ dst, int koff) {
    __shared__ float tl[32][33];
    const int tx = threadIdx.x, ty = threadIdx.y;
    const int k0 = blockIdx.x * 32, n0 = blockIdx.y * 32;
#pragma unroll
    for (int q = 0; q < 4; ++q) {
        int kk = ty * 4 + q;
        tl[kk][tx] = src[(size_t)(k0 + kk) * HDIM + n0 + tx];
    }
    __syncthreads();
#pragma unroll
    for (int q = 0; q < 4; ++q) {
        int nn = ty * 4 + q;
        dst[(size_t)(n0 + nn) * KTOT + koff + k0 + tx] = f2bf(tl[tx][nn]);
    }
}

// Prep: hbuf slot0=bf16(h0); bsum=bx+bh; flags+handshake scratch=0.
__global__ void prep_misc(const float* __restrict__ h0, const float* __restrict__ bx,
                          const float* __restrict__ bh, float* __restrict__ bsum,
                          unsigned short* __restrict__ hbuf, unsigned int* __restrict__ flags) {
    int idx = blockIdx.x * 256 + threadIdx.x;
    if (idx < HBUF_ELEMS) {
        hbuf[idx] = f2bf(h0[idx]);
    } else if (idx < HBUF_ELEMS + HDIM) {
        int j = idx - HBUF_ELEMS;
        bsum[j] = bx[j] + bh[j];
    } else if (idx < HBUF_ELEMS + HDIM + NFLAG + 2 * NBLK) {
        flags[idx - HBUF_ELEMS - HDIM] = 0;
    }
}

__global__ void ws_fail_kernel(float* out) { out[0] = 1.0e6f; }  // ws_size diagnostic

// ---------------------------------------------------------------------------
// R14 = R9 (1601us champion, 128 blocks x 256 threads) + hoisted poll issue.
// Iteration: A0 check (load already in flight since F(t-1)) -> A h+x load
// issue -> B x-MFMA -> C vmcnt(8)+stage+barrier -> D h-MFMA -> E tanh +
// 4x2B h stores (plain in FAST) -> F vmcnt(0) drain + flag publish -> F2
// ISSUE next poll load (RT overlaps G+barrier) -> G x-stage -> barrier.
template<bool FAST>
__device__ __forceinline__ void rnn_loop(
        const float* __restrict__ x, const unsigned short* __restrict__ WT,
        const float* __restrict__ bsum, unsigned short* __restrict__ hbuf,
        unsigned int* __restrict__ flags, float* __restrict__ out,
        unsigned short* xs, unsigned short* hs, const int tid, const int bid) {
    char* xb = (char*)xs;
    char* hb = (char*)hs;
    const int g    = bid & 7;
    const int cb   = bid >> 3;
    const int lane = tid & 63;
    const int wid  = tid >> 6;
    const int lrow = lane & 15;    // A row / C col low bits
    const int kg   = lane >> 4;    // k-group 0..3
    const int ncol = cb * CBW + wid * 16 + lrow;

    // Resident B fragments: lane holds WT[ncol][kc*32 + kg*8 .. +7]
    short8 Bf[48];
    {
        const short8* wp = (const short8*)(WT + (size_t)ncol * KTOT);
#pragma unroll
        for (int kc = 0; kc < 48; ++kc) Bf[kc] = wp[kc * 4 + kg];
    }
#pragma unroll
    for (int kc = 0; kc < 48; ++kc) asm volatile("" : "+v"(Bf[kc]));
    const float bias = bsum[ncol];

    const int sm  = tid & 15;      // staged row 0..15
    const int seg = tid >> 4;      // 1/16 of the row
    unsigned int* const myflag = &flags[(g << 6) + (cb << 2) + wid];
    // wave w's staged columns come from producer blocks 4w..4w+3 only:
    // lane checks flag of producer block (wid*4 + lane>>4), wave sub-flag lane&3
    const unsigned int* const pollp =
        &flags[(g << 6) + (((wid << 2) + (lane >> 4)) << 2) + (lane & 3)];
    const size_t rowoff = (size_t)(g * GROWS + sm) * HDIM + seg * 64;

    // ---- prologue: stage x(0) into xs buf 0; issue first poll load ----
    unsigned int pv;
    {
        float4 xv0[8];
        ldx_issue(x + ((size_t)g * GROWS + sm) * IDIM + seg * 32, xv0);
        asm volatile("s_waitcnt vmcnt(0)" ::: "memory");
        __builtin_amdgcn_sched_barrier(0);
#pragma unroll
        for (int q = 0; q < 4; ++q) {
            float4 a = xv0[2 * q], b = xv0[2 * q + 1];
            ushort8 w;
            w[0] = f2bf(a.x); w[1] = f2bf(a.y); w[2] = f2bf(a.z); w[3] = f2bf(a.w);
            w[4] = f2bf(b.x); w[5] = f2bf(b.y); w[6] = f2bf(b.z); w[7] = f2bf(b.w);
            *(ushort8*)(xb + swzX(sm, seg * 64 + q * 16)) = w;
        }
        pv = ld_u32_issue_if(pollp);           // first poll, in flight over barrier
        asm volatile("s_waitcnt lgkmcnt(0)" ::: "memory");
        __builtin_amdgcn_s_barrier();
        __builtin_amdgcn_sched_barrier(0);
    }

    for (int t = 0; t < T_STEPS; ++t) {
        const bool has_next = (t + 1 < T_STEPS);

        // ---- A0: consume the in-flight poll load (issued at F2(t-1), RT
        // hidden under G + barrier). Monotone flags: stale read just retries. ----
        {
            const unsigned int tgt = (unsigned int)t;
            asm volatile("s_waitcnt vmcnt(0)" ::: "memory");
            __builtin_amdgcn_sched_barrier(0);
            while (!__all(pv >= tgt)) pv = ld_u32_if(pollp);
        }

        // ---- A: issue h(t) loads FIRST (oldest in queue), then x(t+1) ----
        ushort8 hv[8];
        ldh_issue_if(hbuf + (size_t)(t & 1) * HBUF_ELEMS + rowoff, hv);
        float4 xv[8];
        if (has_next)
            ldx_issue(x + ((size_t)(t + 1) * BATCH + g * GROWS + sm) * IDIM + seg * 32, xv);

        // ---- B: x-side MFMA (kc 0..15) under the h/x load latency ----
        const char* xcur = xb + (t & 1) * XBUFB;
        f32x4 acc0 = {0.f, 0.f, 0.f, 0.f}, acc1 = acc0, acc2 = acc0, acc3 = acc0;
#pragma unroll
        for (int kk = 0; kk < 4; ++kk) {
            short8 a0 = *(const short8*)(xcur + swzX(lrow, (4 * kk + 0) * 64 + kg * 16));
            short8 a1 = *(const short8*)(xcur + swzX(lrow, (4 * kk + 1) * 64 + kg * 16));
            short8 a2 = *(const short8*)(xcur + swzX(lrow, (4 * kk + 2) * 64 + kg * 16));
            short8 a3 = *(const short8*)(xcur + swzX(lrow, (4 * kk + 3) * 64 + kg * 16));
            acc0 = __builtin_amdgcn_mfma_f32_16x16x32_bf16(a0, Bf[4 * kk + 0], acc0, 0, 0, 0);
            acc1 = __builtin_amdgcn_mfma_f32_16x16x32_bf16(a1, Bf[4 * kk + 1], acc1, 0, 0, 0);
            acc2 = __builtin_amdgcn_mfma_f32_16x16x32_bf16(a2, Bf[4 * kk + 2], acc2, 0, 0, 0);
            acc3 = __builtin_amdgcn_mfma_f32_16x16x32_bf16(a3, Bf[4 * kk + 3], acc3, 0, 0, 0);
        }

        // ---- C: counted wait = h loads done, x loads keep flying ----
        if (has_next) asm volatile("s_waitcnt vmcnt(8)" ::: "memory");
        else          asm volatile("s_waitcnt vmcnt(0)" ::: "memory");
        __builtin_amdgcn_sched_barrier(0);
#pragma unroll
        for (int q = 0; q < 8; ++q)
            *(ushort8*)(hb + swzH(sm, seg * 128 + q * 16)) = hv[q];
        asm volatile("s_waitcnt lgkmcnt(0)" ::: "memory");
        __builtin_amdgcn_s_barrier();          // raw: no auto vmcnt(0) drain
        __builtin_amdgcn_sched_barrier(0);

        // ---- D: h-side MFMA (kc 16..47) ----
#pragma unroll
        for (int kk = 4; kk < 12; ++kk) {
            short8 a0 = *(const short8*)(hb + swzH(lrow, (4 * kk - 16 + 0) * 64 + kg * 16));
            short8 a1 = *(const short8*)(hb + swzH(lrow, (4 * kk - 16 + 1) * 64 + kg * 16));
            short8 a2 = *(const short8*)(hb + swzH(lrow, (4 * kk - 16 + 2) * 64 + kg * 16));
            short8 a3 = *(const short8*)(hb + swzH(lrow, (4 * kk - 16 + 3) * 64 + kg * 16));
            acc0 = __builtin_amdgcn_mfma_f32_16x16x32_bf16(a0, Bf[4 * kk + 0], acc0, 0, 0, 0);
            acc1 = __builtin_amdgcn_mfma_f32_16x16x32_bf16(a1, Bf[4 * kk + 1], acc1, 0, 0, 0);
            acc2 = __builtin_amdgcn_mfma_f32_16x16x32_bf16(a2, Bf[4 * kk + 2], acc2, 0, 0, 0);
            acc3 = __builtin_amdgcn_mfma_f32_16x16x32_bf16(a3, Bf[4 * kk + 3], acc3, 0, 0, 0);
        }

        // ---- E: epilogue. C row = kg*4 + r, col = ncol (R0 store layout:
        // quarter-wave lanes write 32B-contiguous runs; R6 proved C^T worse) ----
        if (!has_next) {
#pragma unroll
            for (int r = 0; r < 4; ++r) {
                float pre = acc0[r] + acc1[r] + acc2[r] + acc3[r] + bias;
                out[(size_t)(g * GROWS + kg * 4 + r) * HDIM + ncol] = fast_tanh(pre);
            }
            break;
        }
        {
            unsigned short* hdst = hbuf + (size_t)((t + 1) & 1) * HBUF_ELEMS;
#pragma unroll
            for (int r = 0; r < 4; ++r) {
                float pre = acc0[r] + acc1[r] + acc2[r] + acc3[r] + bias;
                float hvf = fast_tanh(pre);
                st_h16_c<FAST>(hdst + (size_t)(g * GROWS + kg * 4 + r) * HDIM + ncol, f2bf(hvf));
            }
        }

        // ---- F: drain stores (L2 acks in FAST) then publish IMMEDIATELY
        // (R10 lesson: nothing between drain and publish) ----
        asm volatile("s_waitcnt vmcnt(0)" ::: "memory");
        __builtin_amdgcn_sched_barrier(0);
        if (lane == 0) st_u32_c<FAST>(myflag, (unsigned int)(t + 1));

        // ---- F2: issue next poll load NOW — its L2 RT overlaps G + barrier ----
        pv = ld_u32_issue_if(pollp);

        // ---- G: stage x(t+1) regs -> xs[(t+1)&1] (no waits) ----
        {
            char* xnxt = xb + ((t + 1) & 1) * XBUFB;
#pragma unroll
            for (int q = 0; q < 4; ++q) {
                float4 a = xv[2 * q], b = xv[2 * q + 1];
                ushort8 w;
                w[0] = f2bf(a.x); w[1] = f2bf(a.y); w[2] = f2bf(a.z); w[3] = f2bf(a.w);
                w[4] = f2bf(b.x); w[5] = f2bf(b.y); w[6] = f2bf(b.z); w[7] = f2bf(b.w);
                *(ushort8*)(xnxt + swzX(sm, seg * 64 + q * 16)) = w;
            }
        }

        // ---- loop end: hs/xs reuse guard ----
        asm volatile("s_waitcnt lgkmcnt(0)" ::: "memory");
        __builtin_amdgcn_s_barrier();
        __builtin_amdgcn_sched_barrier(0);
    }
}

// ---------------------------------------------------------------------------
// Handshake (completed on HW, R8/R9): exchange HW_REG_XCC_ID via the proven
// sc0 sc1 path; all 128 blocks co-resident (1 block/CU). Same-XCD group ->
// FAST (plain h + flag stores, L2-ack drains); else all-sc0sc1 SLOW path.
__global__ __launch_bounds__(256, 1) void rnn_fused(
        const float* __restrict__ x, const unsigned short* __restrict__ WT,
        const float* __restrict__ bsum, unsigned short* __restrict__ hbuf,
        unsigned int* __restrict__ flags, float* __restrict__ out) {
    __shared__ unsigned short xs[2 * GROWS * IDIM];   // 32 KB (double-buffered x tile)
    __shared__ unsigned short hs[GROWS * HDIM];       // 32 KB (h tile)
    const int tid  = threadIdx.x;
    const int bid  = blockIdx.x;
    const int g    = bid & 7;
    const int lane = tid & 63;

    unsigned int myxcd;
    asm volatile("s_getreg_b32 %0, hwreg(HW_REG_XCC_ID)" : "=s"(myxcd));
    unsigned int* const xcdmap = flags + NFLAG;          // [NBLK]
    unsigned int* const hsflag = flags + NFLAG + NBLK;   // [NBLK]
    if (tid == 0) {
        st_u32_if(&xcdmap[bid], myxcd + 1u);
        asm volatile("s_waitcnt vmcnt(0)" ::: "memory");
        st_u32_if(&hsflag[bid], 1u);
    }
    // peers of group g are bids g, g+8, ..., g+120; lanes 16..63 duplicate
    const int peer = g + 8 * (lane & 15);
    while (true) {
        unsigned int v = ld_u32_if(&hsflag[peer]);
        if (__all(v != 0)) break;
    }
    const unsigned int px = ld_u32_if(&xcdmap[peer]);
    // verdict symmetric across the group (same 16 values) -> same path chosen
    if (__all(px == myxcd + 1u))
        rnn_loop<true >(x, WT, bsum, hbuf, flags, out, xs, hs, tid, bid);
    else
        rnn_loop<false>(x, WT, bsum, hbuf, flags, out, xs, hs, tid, bid);
}

// ---------------------------------------------------------------------------
extern "C" void kernel_launch(void* const* d_in, const int* in_sizes, int n_in,
                              void* d_out, int out_size, void* d_ws, size_t ws_size,
                              hipStream_t stream) {
    const float* x  = (const float*)d_in[0];
    const float* h0 = (const float*)d_in[1];
    const float* Wx = (const float*)d_in[2];
    const float* bx = (const float*)d_in[3];
    const float* Wh = (const float*)d_in[4];
    const float* bh = (const float*)d_in[5];
    float* out = (float*)d_out;

    // workspace layout (128B-aligned pieces)
    const size_t OFF_WT = 0;                    // 1024*1536 bf16 = 3,145,728 B
    const size_t OFF_BS = 3145728;              // 1024 f32 = 4096 B
    const size_t OFF_HB = 3149824;              // 2*128*1024 bf16 = 524,288 B
    const size_t OFF_FL = 3674112;              // (512 + 256) u32 = 3072 B
    const size_t WS_NEED = 3677184;
    if (ws_size < WS_NEED) {                    // diagnostic: absmax ~1e6 => ws too small
        hipLaunchKernelGGL(ws_fail_kernel, dim3(1), dim3(1), 0, stream, out);
        return;
    }

    unsigned short* WT    = (unsigned short*)((char*)d_ws + OFF_WT);
    float*          bsum  = (float*)((char*)d_ws + OFF_BS);
    unsigned short* hbuf  = (unsigned short*)((char*)d_ws + OFF_HB);
    unsigned int*   flags = (unsigned int*)((char*)d_ws + OFF_FL);

    prep_transpose<<<dim3(IDIM / 32, HDIM / 32), dim3(32, 8), 0, stream>>>(Wx, WT, 0);
    prep_transpose<<<dim3(HDIM / 32, HDIM / 32), dim3(32, 8), 0, stream>>>(Wh, WT, IDIM);
    const int misc_total = HBUF_ELEMS + HDIM + NFLAG + 2 * NBLK;
    prep_misc<<<dim3((misc_total + 255) / 256), dim3(256), 0, stream>>>(
        h0, bx, bh, bsum, hbuf, flags);
    rnn_fused<<<dim3(NBLK), dim3(256), 0, stream>>>(
        x, WT, bsum, hbuf, flags, out);
}

// Round 15
// 1593.929 us; speedup vs baseline: 2.1444x; 1.0258x over previous
//
#include <hip/hip_runtime.h>
#include <hip/hip_bf16.h>

typedef __attribute__((ext_vector_type(4))) float f32x4;
typedef __attribute__((ext_vector_type(8))) short short8;
typedef __attribute__((ext_vector_type(8))) unsigned short ushort8;

#define T_STEPS 512
#define BATCH   128
#define IDIM    512
#define HDIM    1024
#define KTOT    1536           // IDIM + HDIM (fused [x_t | h] @ [Wx; Wh])
#define NGROUP  8              // batch groups (16 rows each)
#define GROWS   16             // batch rows per group
#define NCB     16             // column-blocks per group
#define CBW     64             // output columns per block (4 waves x 16)
#define NBLK    (NGROUP * NCB) // 128 blocks
#define HBUF_ELEMS (BATCH * HDIM)
#define XBUFB   (GROWS * IDIM * 2)   // bytes per xs half
#define NFLAG   (NGROUP * 64)        // per-WAVE flags, packed 4B (coalesced polls)
// handshake scratch appended after flags: xcdmap[NBLK], hsflag[NBLK]

// f32 -> bf16 round-to-nearest-even
__device__ __forceinline__ unsigned short f2bf(float f) {
    unsigned int u = __builtin_bit_cast(unsigned int, f);
    u = (u + 0x7FFFu + ((u >> 16) & 1u)) >> 16;
    return (unsigned short)u;
}

// fast tanh: clamp +-9, e2x = exp2(2*log2e*x), (e2x-1)*rcp(e2x+1).
__device__ __forceinline__ float fast_tanh(float x) {
    x = fminf(9.0f, fmaxf(-9.0f, x));
    float t = __builtin_exp2f(x * 2.8853900817779268f);
    return (t - 1.0f) * __builtin_amdgcn_rcpf(t + 1.0f);
}

// XOR swizzles (row strides 0 mod 128B; XOR row low-bits into the 16B-slot index)
__device__ __forceinline__ int swzX(int row, int c) { return row * 1024 + (c ^ ((row & 7) << 4)); }
__device__ __forceinline__ int swzH(int row, int c) { return row * 2048 + (c ^ ((row & 7) << 4)); }

// ---- coherence primitives ---------------------------------------------------
// Session model (validated R8+R9): sc0 sc1 STORES write through to HBM and
// their vmcnt ack costs ~1100cy; PLAIN stores ack at the shared same-XCD L2
// (~250cy) and sc0 sc1 (L1-bypassing) consumer loads dirty-hit that line.
// R8: h-data plain (WRITE 139.5->9.2MB, -182us). R9: flag publish plain
// (WRITE ->1MB, -387us). Both absmax-clean. FAST requires same-XCD
// (handshake-gated); SLOW keeps everything sc0 sc1 (exact R0).
// Perturbation record (all regressed or blocked): tail reorder (R10 +30us),
// poll hoist (R14 +34us), fan-1 512t geometry (R11-13 allocator-blocked),
// elastic waves (R7 +35%), packed C^T epilogue (R6 +12%), sleep pacing (R3).
// R9 is the measured local optimum of this protocol family.
__device__ __forceinline__ void st_u32_if(unsigned int* p, unsigned int v) {
    asm volatile("global_store_dword %0, %1, off sc0 sc1" :: "v"(p), "v"(v) : "memory");
}
template<bool FAST>
__device__ __forceinline__ void st_u32_c(unsigned int* p, unsigned int v) {
    if (FAST) asm volatile("global_store_dword %0, %1, off" :: "v"(p), "v"(v) : "memory");
    else      asm volatile("global_store_dword %0, %1, off sc0 sc1" :: "v"(p), "v"(v) : "memory");
}
template<bool FAST>
__device__ __forceinline__ void st_h16_c(unsigned short* p, unsigned short v) {
    if (FAST) asm volatile("global_store_short %0, %1, off" :: "v"(p), "v"(v) : "memory");
    else      asm volatile("global_store_short %0, %1, off sc0 sc1" :: "v"(p), "v"(v) : "memory");
}
__device__ __forceinline__ unsigned int ld_u32_if(const unsigned int* p) {
    unsigned int v;
    asm volatile("global_load_dword %0, %1, off sc0 sc1\n\ts_waitcnt vmcnt(0)"
                 : "=v"(v) : "v"(p) : "memory");
    return v;
}
// issue 8 pipelined dwordx4 h-tile loads (128 B), NO wait (drained by counted vmcnt)
__device__ __forceinline__ void ldh_issue_if(const unsigned short* p, ushort8 v[8]) {
    asm volatile(
        "global_load_dwordx4 %0, %8, off sc0 sc1\n\t"
        "global_load_dwordx4 %1, %8, off offset:16 sc0 sc1\n\t"
        "global_load_dwordx4 %2, %8, off offset:32 sc0 sc1\n\t"
        "global_load_dwordx4 %3, %8, off offset:48 sc0 sc1\n\t"
        "global_load_dwordx4 %4, %8, off offset:64 sc0 sc1\n\t"
        "global_load_dwordx4 %5, %8, off offset:80 sc0 sc1\n\t"
        "global_load_dwordx4 %6, %8, off offset:96 sc0 sc1\n\t"
        "global_load_dwordx4 %7, %8, off offset:112 sc0 sc1"
        : "=&v"(v[0]), "=&v"(v[1]), "=&v"(v[2]), "=&v"(v[3]),
          "=&v"(v[4]), "=&v"(v[5]), "=&v"(v[6]), "=&v"(v[7])
        : "v"(p) : "memory");
}
// issue 8 pipelined dwordx4 x-tile loads (128 B of f32), normal caching, NO wait
__device__ __forceinline__ void ldx_issue(const float* p, float4 v[8]) {
    asm volatile(
        "global_load_dwordx4 %0, %8, off\n\t"
        "global_load_dwordx4 %1, %8, off offset:16\n\t"
        "global_load_dwordx4 %2, %8, off offset:32\n\t"
        "global_load_dwordx4 %3, %8, off offset:48\n\t"
        "global_load_dwordx4 %4, %8, off offset:64\n\t"
        "global_load_dwordx4 %5, %8, off offset:80\n\t"
        "global_load_dwordx4 %6, %8, off offset:96\n\t"
        "global_load_dwordx4 %7, %8, off offset:112"
        : "=&v"(v[0]), "=&v"(v[1]), "=&v"(v[2]), "=&v"(v[3]),
          "=&v"(v[4]), "=&v"(v[5]), "=&v"(v[6]), "=&v"(v[7])
        : "v"(p) : "memory");
}

// ---------------------------------------------------------------------------
// Prep: WT[n][k] = bf16(W[k][n]) for W in {Wx (koff=0), Wh (koff=IDIM)}.
__global__ void prep_transpose(const float* __restrict__ src,
                               unsigned short* __restrict__ dst, int koff) {
    __shared__ float tl[32][33];
    const int tx = threadIdx.x, ty = threadIdx.y;
    const int k0 = blockIdx.x * 32, n0 = blockIdx.y * 32;
#pragma unroll
    for (int q = 0; q < 4; ++q) {
        int kk = ty * 4 + q;
        tl[kk][tx] = src[(size_t)(k0 + kk) * HDIM + n0 + tx];
    }
    __syncthreads();
#pragma unroll
    for (int q = 0; q < 4; ++q) {
        int nn = ty * 4 + q;
        dst[(size_t)(n0 + nn) * KTOT + koff + k0 + tx] = f2bf(tl[tx][nn]);
    }
}

// Prep: hbuf slot0=bf16(h0); bsum=bx+bh; flags+handshake scratch=0. Dispatch-
// end release flushes all L2s before rnn_fused (stream order) — unchanged.
__global__ void prep_misc(const float* __restrict__ h0, const float* __restrict__ bx,
                          const float* __restrict__ bh, float* __restrict__ bsum,
                          unsigned short* __restrict__ hbuf, unsigned int* __restrict__ flags) {
    int idx = blockIdx.x * 256 + threadIdx.x;
    if (idx < HBUF_ELEMS) {
        hbuf[idx] = f2bf(h0[idx]);
    } else if (idx < HBUF_ELEMS + HDIM) {
        int j = idx - HBUF_ELEMS;
        bsum[j] = bx[j] + bh[j];
    } else if (idx < HBUF_ELEMS + HDIM + NFLAG + 2 * NBLK) {
        flags[idx - HBUF_ELEMS - HDIM] = 0;
    }
}

__global__ void ws_fail_kernel(float* out) { out[0] = 1.0e6f; }  // ws_size diagnostic

// ---------------------------------------------------------------------------
// R9 champion loop (1601us). Iteration: A0 quartet poll -> A h+x load issue
// -> B x-MFMA -> C vmcnt(8)+stage+barrier -> D h-MFMA -> E tanh + 4x2B h
// stores (plain in FAST) -> F vmcnt(0) drain (L2 ack) + flag publish (plain
// in FAST; its ack is drained by the next poll's vmcnt(0)) -> G x-stage ->
// loop-end barrier.
template<bool FAST>
__device__ __forceinline__ void rnn_loop(
        const float* __restrict__ x, const unsigned short* __restrict__ WT,
        const float* __restrict__ bsum, unsigned short* __restrict__ hbuf,
        unsigned int* __restrict__ flags, float* __restrict__ out,
        unsigned short* xs, unsigned short* hs, const int tid, const int bid) {
    char* xb = (char*)xs;
    char* hb = (char*)hs;
    const int g    = bid & 7;
    const int cb   = bid >> 3;
    const int lane = tid & 63;
    const int wid  = tid >> 6;
    const int lrow = lane & 15;    // A row / C col low bits
    const int kg   = lane >> 4;    // k-group 0..3
    const int ncol = cb * CBW + wid * 16 + lrow;

    // Resident B fragments: lane holds WT[ncol][kc*32 + kg*8 .. +7]
    short8 Bf[48];
    {
        const short8* wp = (const short8*)(WT + (size_t)ncol * KTOT);
#pragma unroll
        for (int kc = 0; kc < 48; ++kc) Bf[kc] = wp[kc * 4 + kg];
    }
#pragma unroll
    for (int kc = 0; kc < 48; ++kc) asm volatile("" : "+v"(Bf[kc]));
    const float bias = bsum[ncol];

    const int sm  = tid & 15;      // staged row 0..15
    const int seg = tid >> 4;      // 1/16 of the row
    unsigned int* const myflag = &flags[(g << 6) + (cb << 2) + wid];
    // wave w's staged columns come from producer blocks 4w..4w+3 only:
    // lane checks flag of producer block (wid*4 + lane>>4), wave sub-flag lane&3
    const unsigned int* const pollp =
        &flags[(g << 6) + (((wid << 2) + (lane >> 4)) << 2) + (lane & 3)];
    const size_t rowoff = (size_t)(g * GROWS + sm) * HDIM + seg * 64;

    // ---- prologue: stage x(0) into xs buf 0 (deterministic queue: drain) ----
    {
        float4 xv0[8];
        ldx_issue(x + ((size_t)g * GROWS + sm) * IDIM + seg * 32, xv0);
        asm volatile("s_waitcnt vmcnt(0)" ::: "memory");
        __builtin_amdgcn_sched_barrier(0);
#pragma unroll
        for (int q = 0; q < 4; ++q) {
            float4 a = xv0[2 * q], b = xv0[2 * q + 1];
            ushort8 w;
            w[0] = f2bf(a.x); w[1] = f2bf(a.y); w[2] = f2bf(a.z); w[3] = f2bf(a.w);
            w[4] = f2bf(b.x); w[5] = f2bf(b.y); w[6] = f2bf(b.z); w[7] = f2bf(b.w);
            *(ushort8*)(xb + swzX(sm, seg * 64 + q * 16)) = w;
        }
        asm volatile("s_waitcnt lgkmcnt(0)" ::: "memory");
        __builtin_amdgcn_s_barrier();
        __builtin_amdgcn_sched_barrier(0);
    }

    for (int t = 0; t < T_STEPS; ++t) {
        const bool has_next = (t + 1 < T_STEPS);

        // ---- A0: per-wave quartet poll (flags carry value t after F(t-1)) ----
        {
            const unsigned int tgt = (unsigned int)t;
            while (true) {
                unsigned int v = ld_u32_if(pollp);
                if (__all(v >= tgt)) break;    // no s_sleep: vmcnt RT paces the loop
            }
        }

        // ---- A: issue h(t) loads FIRST (oldest in queue), then x(t+1) ----
        ushort8 hv[8];
        ldh_issue_if(hbuf + (size_t)(t & 1) * HBUF_ELEMS + rowoff, hv);
        float4 xv[8];
        if (has_next)
            ldx_issue(x + ((size_t)(t + 1) * BATCH + g * GROWS + sm) * IDIM + seg * 32, xv);

        // ---- B: x-side MFMA (kc 0..15) under the h/x load latency ----
        const char* xcur = xb + (t & 1) * XBUFB;
        f32x4 acc0 = {0.f, 0.f, 0.f, 0.f}, acc1 = acc0, acc2 = acc0, acc3 = acc0;
#pragma unroll
        for (int kk = 0; kk < 4; ++kk) {
            short8 a0 = *(const short8*)(xcur + swzX(lrow, (4 * kk + 0) * 64 + kg * 16));
            short8 a1 = *(const short8*)(xcur + swzX(lrow, (4 * kk + 1) * 64 + kg * 16));
            short8 a2 = *(const short8*)(xcur + swzX(lrow, (4 * kk + 2) * 64 + kg * 16));
            short8 a3 = *(const short8*)(xcur + swzX(lrow, (4 * kk + 3) * 64 + kg * 16));
            acc0 = __builtin_amdgcn_mfma_f32_16x16x32_bf16(a0, Bf[4 * kk + 0], acc0, 0, 0, 0);
            acc1 = __builtin_amdgcn_mfma_f32_16x16x32_bf16(a1, Bf[4 * kk + 1], acc1, 0, 0, 0);
            acc2 = __builtin_amdgcn_mfma_f32_16x16x32_bf16(a2, Bf[4 * kk + 2], acc2, 0, 0, 0);
            acc3 = __builtin_amdgcn_mfma_f32_16x16x32_bf16(a3, Bf[4 * kk + 3], acc3, 0, 0, 0);
        }

        // ---- C: counted wait = h loads done, x loads keep flying ----
        if (has_next) asm volatile("s_waitcnt vmcnt(8)" ::: "memory");
        else          asm volatile("s_waitcnt vmcnt(0)" ::: "memory");
        __builtin_amdgcn_sched_barrier(0);
#pragma unroll
        for (int q = 0; q < 8; ++q)
            *(ushort8*)(hb + swzH(sm, seg * 128 + q * 16)) = hv[q];
        asm volatile("s_waitcnt lgkmcnt(0)" ::: "memory");
        __builtin_amdgcn_s_barrier();          // raw: no auto vmcnt(0) drain
        __builtin_amdgcn_sched_barrier(0);

        // ---- D: h-side MFMA (kc 16..47) ----
#pragma unroll
        for (int kk = 4; kk < 12; ++kk) {
            short8 a0 = *(const short8*)(hb + swzH(lrow, (4 * kk - 16 + 0) * 64 + kg * 16));
            short8 a1 = *(const short8*)(hb + swzH(lrow, (4 * kk - 16 + 1) * 64 + kg * 16));
            short8 a2 = *(const short8*)(hb + swzH(lrow, (4 * kk - 16 + 2) * 64 + kg * 16));
            short8 a3 = *(const short8*)(hb + swzH(lrow, (4 * kk - 16 + 3) * 64 + kg * 16));
            acc0 = __builtin_amdgcn_mfma_f32_16x16x32_bf16(a0, Bf[4 * kk + 0], acc0, 0, 0, 0);
            acc1 = __builtin_amdgcn_mfma_f32_16x16x32_bf16(a1, Bf[4 * kk + 1], acc1, 0, 0, 0);
            acc2 = __builtin_amdgcn_mfma_f32_16x16x32_bf16(a2, Bf[4 * kk + 2], acc2, 0, 0, 0);
            acc3 = __builtin_amdgcn_mfma_f32_16x16x32_bf16(a3, Bf[4 * kk + 3], acc3, 0, 0, 0);
        }

        // ---- E: epilogue. C row = kg*4 + r, col = ncol (R0 store layout:
        // quarter-wave lanes write 32B-contiguous runs; R6 proved C^T worse) ----
        if (!has_next) {
#pragma unroll
            for (int r = 0; r < 4; ++r) {
                float pre = acc0[r] + acc1[r] + acc2[r] + acc3[r] + bias;
                out[(size_t)(g * GROWS + kg * 4 + r) * HDIM + ncol] = fast_tanh(pre);
            }
            break;
        }
        {
            unsigned short* hdst = hbuf + (size_t)((t + 1) & 1) * HBUF_ELEMS;
#pragma unroll
            for (int r = 0; r < 4; ++r) {
                float pre = acc0[r] + acc1[r] + acc2[r] + acc3[r] + bias;
                float hvf = fast_tanh(pre);
                st_h16_c<FAST>(hdst + (size_t)(g * GROWS + kg * 4 + r) * HDIM + ncol, f2bf(hvf));
            }
        }

        // ---- F: drain stores (L2 ack in FAST) then publish IMMEDIATELY
        // (R10 lesson: nothing between drain and publish). Flag store plain
        // in FAST: h-data already committed to L2 by the drain above; its own
        // ack is paid at the next poll's vmcnt(0) — ~250cy not ~1100.
        asm volatile("s_waitcnt vmcnt(0)" ::: "memory");
        __builtin_amdgcn_sched_barrier(0);
        if (lane == 0) st_u32_c<FAST>(myflag, (unsigned int)(t + 1));

        // ---- G: stage x(t+1) regs -> xs[(t+1)&1] (no waits) ----
        {
            char* xnxt = xb + ((t + 1) & 1) * XBUFB;
#pragma unroll
            for (int q = 0; q < 4; ++q) {
                float4 a = xv[2 * q], b = xv[2 * q + 1];
                ushort8 w;
                w[0] = f2bf(a.x); w[1] = f2bf(a.y); w[2] = f2bf(a.z); w[3] = f2bf(a.w);
                w[4] = f2bf(b.x); w[5] = f2bf(b.y); w[6] = f2bf(b.z); w[7] = f2bf(b.w);
                *(ushort8*)(xnxt + swzX(sm, seg * 64 + q * 16)) = w;
            }
        }

        // ---- loop end: hs/xs reuse guard ----
        asm volatile("s_waitcnt lgkmcnt(0)" ::: "memory");
        __builtin_amdgcn_s_barrier();
        __builtin_amdgcn_sched_barrier(0);
    }
}

// ---------------------------------------------------------------------------
// Handshake (completed on HW, R8/R9): exchange HW_REG_XCC_ID via the proven
// sc0 sc1 path; all 128 blocks co-resident (1 block/CU). Same-XCD group ->
// FAST (plain h + flag stores, L2-ack drains); else all-sc0sc1 SLOW path.
__global__ __launch_bounds__(256, 1) void rnn_fused(
        const float* __restrict__ x, const unsigned short* __restrict__ WT,
        const float* __restrict__ bsum, unsigned short* __restrict__ hbuf,
        unsigned int* __restrict__ flags, float* __restrict__ out) {
    __shared__ unsigned short xs[2 * GROWS * IDIM];   // 32 KB (double-buffered x tile)
    __shared__ unsigned short hs[GROWS * HDIM];       // 32 KB (h tile)
    const int tid  = threadIdx.x;
    const int bid  = blockIdx.x;
    const int g    = bid & 7;
    const int lane = tid & 63;

    unsigned int myxcd;
    asm volatile("s_getreg_b32 %0, hwreg(HW_REG_XCC_ID)" : "=s"(myxcd));
    unsigned int* const xcdmap = flags + NFLAG;          // [NBLK]
    unsigned int* const hsflag = flags + NFLAG + NBLK;   // [NBLK]
    if (tid == 0) {
        st_u32_if(&xcdmap[bid], myxcd + 1u);
        asm volatile("s_waitcnt vmcnt(0)" ::: "memory");
        st_u32_if(&hsflag[bid], 1u);
    }
    // peers of group g are bids g, g+8, ..., g+120; lanes 16..63 duplicate
    const int peer = g + 8 * (lane & 15);
    while (true) {
        unsigned int v = ld_u32_if(&hsflag[peer]);
        if (__all(v != 0)) break;
    }
    const unsigned int px = ld_u32_if(&xcdmap[peer]);
    // verdict symmetric across the group (same 16 values) -> same path chosen
    if (__all(px == myxcd + 1u))
        rnn_loop<true >(x, WT, bsum, hbuf, flags, out, xs, hs, tid, bid);
    else
        rnn_loop<false>(x, WT, bsum, hbuf, flags, out, xs, hs, tid, bid);
}

// ---------------------------------------------------------------------------
extern "C" void kernel_launch(void* const* d_in, const int* in_sizes, int n_in,
                              void* d_out, int out_size, void* d_ws, size_t ws_size,
                              hipStream_t stream) {
    const float* x  = (const float*)d_in[0];
    const float* h0 = (const float*)d_in[1];
    const float* Wx = (const float*)d_in[2];
    const float* bx = (const float*)d_in[3];
    const float* Wh = (const float*)d_in[4];
    const float* bh = (const float*)d_in[5];
    float* out = (float*)d_out;

    // workspace layout (128B-aligned pieces)
    const size_t OFF_WT = 0;                    // 1024*1536 bf16 = 3,145,728 B
    const size_t OFF_BS = 3145728;              // 1024 f32 = 4096 B
    const size_t OFF_HB = 3149824;              // 2*128*1024 bf16 = 524,288 B
    const size_t OFF_FL = 3674112;              // (512 + 256) u32 = 3072 B
    const size_t WS_NEED = 3677184;
    if (ws_size < WS_NEED) {                    // diagnostic: absmax ~1e6 => ws too small
        hipLaunchKernelGGL(ws_fail_kernel, dim3(1), dim3(1), 0, stream, out);
        return;
    }

    unsigned short* WT    = (unsigned short*)((char*)d_ws + OFF_WT);
    float*          bsum  = (float*)((char*)d_ws + OFF_BS);
    unsigned short* hbuf  = (unsigned short*)((char*)d_ws + OFF_HB);
    unsigned int*   flags = (unsigned int*)((char*)d_ws + OFF_FL);

    prep_transpose<<<dim3(IDIM / 32, HDIM / 32), dim3(32, 8), 0, stream>>>(Wx, WT, 0);
    prep_transpose<<<dim3(HDIM / 32, HDIM / 32), dim3(32, 8), 0, stream>>>(Wh, WT, IDIM);
    const int misc_total = HBUF_ELEMS + HDIM + NFLAG + 2 * NBLK;
    prep_misc<<<dim3((misc_total + 255) / 256), dim3(256), 0, stream>>>(
        h0, bx, bh, bsum, hbuf, flags);
    rnn_fused<<<dim3(NBLK), dim3(256), 0, stream>>>(
        x, WT, bsum, hbuf, flags, out);
}